// Round 3
// baseline (16089.577 us; speedup 1.0000x reference)
//
#include <hip/hip_runtime.h>

// BiLSTM(128->2x256) -> LayerNorm(512) -> BiLSTM(512->2x256), B=64 T=1024.
// ALL matmul inputs in f16 (11-bit mantissa; values here are tiny so no range
// risk) -> 8x less rounding error than bf16 at identical MFMA throughput.
// f32 cell state and f32 MFMA accumulation. Input projections as batched
// GEMMs into transposed zx buffers (f16); recurrences run in a persistent
// 32-WG kernel (2 dirs x 4 batch-groups x 4 u-slices) with recurrent weights
// resident in VGPRs and per-step h exchange via global memory + flags.

typedef __attribute__((ext_vector_type(8))) _Float16 half8;    // f16x8 MFMA frag
typedef __attribute__((ext_vector_type(4))) float f32x4;       // MFMA acc
typedef __attribute__((ext_vector_type(4))) unsigned short ushort4v;

#define LOG2E 1.4426950408889634f

static __device__ __forceinline__ unsigned short f2h(float f) {
  _Float16 h = (_Float16)f;                       // v_cvt_f16_f32 (RTN)
  return __builtin_bit_cast(unsigned short, h);
}
static __device__ __forceinline__ float h2f(unsigned short u) {
  _Float16 h = __builtin_bit_cast(_Float16, u);
  return (float)h;                                // v_cvt_f32_f16
}
static __device__ __forceinline__ float sigf(float x) {
  return __builtin_amdgcn_rcpf(1.f + __builtin_amdgcn_exp2f(-LOG2E * x));
}
static __device__ __forceinline__ float tanhf_(float x) {
  return 1.f - 2.f * __builtin_amdgcn_rcpf(__builtin_amdgcn_exp2f((2.f * LOG2E) * x) + 1.f);
}

__global__ void k_init(int* flags) {
  if (threadIdx.x < 64) flags[threadIdx.x] = 0;
}

// out[c][k] = f16(in[k][c]); in is [K][1024] f32, out is [1024][K] f16.
__global__ void k_transpose(const float* __restrict__ in, unsigned short* __restrict__ out, int K) {
  int idx = blockIdx.x * 256 + threadIdx.x;   // idx = c*K + k
  int c = idx / K, k = idx - c * K;
  out[idx] = f2h(in[k * 1024 + c]);
}

// x [b][t][128] f32 -> xb [(t*64+b)][128] f16
__global__ void k_cvtx(const float* __restrict__ x, unsigned short* __restrict__ xb) {
  int i = blockIdx.x * 256 + threadIdx.x;
  int o = i * 4;
  int k = o & 127, row = o >> 7;            // row = t*64+b
  int b = row & 63, t = row >> 6;
  const f32x4 v = *(const f32x4*)(x + (size_t)((b << 10) + t) * 128 + k);
  ushort4v r;
  r.x = f2h(v.x); r.y = f2h(v.y); r.z = f2h(v.z); r.w = f2h(v.w);
  *(ushort4v*)(xb + o) = r;
}

// zx GEMM: A [65536 rows=(t*64+b)][K] f16 times Wt [1024][K] f16 (+bias)
// -> out [1024 t][1024 col][64 b] f16.  128x128 tiles, direct-global frags.
template<int K>
__global__ __launch_bounds__(256, 2) void k_zx(
    const unsigned short* __restrict__ A,
    const unsigned short* __restrict__ Wt_f, const unsigned short* __restrict__ Wt_b,
    const float* __restrict__ bias_f, const float* __restrict__ bias_b,
    unsigned short* __restrict__ out_f, unsigned short* __restrict__ out_b) {
  const int tid = threadIdx.x, w = tid >> 6, l = tid & 63;
  const int l16 = l & 15, lg = l >> 4;
  const int wm = w & 1, wn = w >> 1;
  const int rowbase = blockIdx.x * 128 + wm * 64;
  const int colbase = blockIdx.y * 128 + wn * 64;
  const unsigned short* Wt = blockIdx.z ? Wt_b : Wt_f;
  const float* bias = blockIdx.z ? bias_b : bias_f;
  unsigned short* out = blockIdx.z ? out_b : out_f;

  f32x4 acc[4][4];
#pragma unroll
  for (int nt = 0; nt < 4; nt++) {
    float bv = bias[colbase + nt * 16 + l16];
#pragma unroll
    for (int mt = 0; mt < 4; mt++) acc[mt][nt] = (f32x4){bv, bv, bv, bv};
  }

  for (int kf = 0; kf < K / 32; kf++) {
    const int ko = kf * 32 + lg * 8;
    half8 a[4], b[4];
#pragma unroll
    for (int mt = 0; mt < 4; mt++)
      a[mt] = *(const half8*)(A + (size_t)(rowbase + mt * 16 + l16) * K + ko);
#pragma unroll
    for (int nt = 0; nt < 4; nt++)
      b[nt] = *(const half8*)(Wt + (size_t)(colbase + nt * 16 + l16) * K + ko);
#pragma unroll
    for (int mt = 0; mt < 4; mt++)
#pragma unroll
      for (int nt = 0; nt < 4; nt++)
        acc[mt][nt] = __builtin_amdgcn_mfma_f32_16x16x32_f16(a[mt], b[nt], acc[mt][nt], 0, 0, 0);
  }

#pragma unroll
  for (int mt = 0; mt < 4; mt++) {
    const int rowchunk = rowbase + mt * 16;       // multiple of 16, within one t
    const int t = rowchunk >> 6;
    const int b0 = (rowchunk & 63) + lg * 4;
#pragma unroll
    for (int nt = 0; nt < 4; nt++) {
      const int c = colbase + nt * 16 + l16;
      ushort4v r;
      r.x = f2h(acc[mt][nt].x); r.y = f2h(acc[mt][nt].y);
      r.z = f2h(acc[mt][nt].z); r.w = f2h(acc[mt][nt].w);
      *(ushort4v*)(out + (((size_t)t << 10 | c) << 6) + b0) = r;
    }
  }
}

// Persistent recurrent kernel. 32 blocks: bid = s*8 + d*4 + g
//   s: u-slice (64 u each), d: direction, g: batch-group (16 batches).
// Per step: z = zx[t] + h_{t-1} @ U(slice); gates; h,c update; publish h slice.
template<int LAYER>
__global__ __launch_bounds__(256, 1) void k_rec(
    const unsigned short* __restrict__ zx_f, const unsigned short* __restrict__ zx_b,
    const unsigned short* __restrict__ Ut_f, const unsigned short* __restrict__ Ut_b,
    unsigned short* __restrict__ hbuf,   // [2 dir][2 slot][64 b][256 u] f16
    int* __restrict__ flags,             // [2 dir][4 g][4 s]
    unsigned short* __restrict__ h1,     // LAYER==1: [(t*64+b)][512] f16
    float* __restrict__ out) {           // LAYER==2: [b][t][512] f32
  const int tid = threadIdx.x, w = tid >> 6, l = tid & 63;
  const int l16 = l & 15, lg = l >> 4;
  const int bid = blockIdx.x;
  const int s = bid >> 3, r5 = bid & 7, d = r5 >> 2, g = r5 & 3;
  const int b0 = g * 16;
  const int u = s * 64 + w * 16 + l16;   // this lane's u (col within slice block)

  const unsigned short* zx = d ? zx_b : zx_f;
  const unsigned short* Ut = d ? Ut_b : Ut_f;
  unsigned short* hb_base = hbuf + (size_t)d * 2 * 64 * 256;
  int* flg = flags + (d * 4 + g) * 4;

  // Recurrent weight fragments, resident in VGPRs: B[q][kf], q = gate i/f/g/o.
  half8 B[4][8];
#pragma unroll
  for (int q = 0; q < 4; q++) {
    const unsigned short* colp = Ut + (size_t)(q * 256 + u) * 256;
#pragma unroll
    for (int kf = 0; kf < 8; kf++)
      B[q][kf] = *(const half8*)(colp + kf * 32 + lg * 8);
  }

  f32x4 c = (f32x4){0.f, 0.f, 0.f, 0.f};

  // prefetch zx for t=0
  ushort4v zq[4];
  {
    const int tt0 = d ? 1023 : 0;
#pragma unroll
    for (int q = 0; q < 4; q++)
      zq[q] = *(const ushort4v*)(zx + (((size_t)tt0 << 10 | (q * 256 + u)) << 6) + b0 + lg * 4);
  }

  for (int t = 0; t < 1024; t++) {
    const int tt = d ? 1023 - t : t;
    f32x4 acc[4];
#pragma unroll
    for (int q = 0; q < 4; q++)
      acc[q] = (f32x4){h2f(zq[q].x), h2f(zq[q].y), h2f(zq[q].z), h2f(zq[q].w)};
    if (t + 1 < 1024) {  // prefetch next step's zx (hides HBM latency)
      const int tn = d ? tt - 1 : tt + 1;
#pragma unroll
      for (int q = 0; q < 4; q++)
        zq[q] = *(const ushort4v*)(zx + (((size_t)tn << 10 | (q * 256 + u)) << 6) + b0 + lg * 4);
    }

    if (t > 0) {
      const unsigned short* hb = hb_base + (size_t)((t - 1) & 1) * 64 * 256 + (size_t)(b0 + l16) * 256;
      // own slice first: no wait needed (written by this WG last step)
      {
        half8 a0 = *(const half8*)(hb + (2 * s) * 32 + lg * 8);
        half8 a1 = *(const half8*)(hb + (2 * s + 1) * 32 + lg * 8);
#pragma unroll
        for (int q = 0; q < 4; q++) acc[q] = __builtin_amdgcn_mfma_f32_16x16x32_f16(a0, B[q][2 * s], acc[q], 0, 0, 0);
#pragma unroll
        for (int q = 0; q < 4; q++) acc[q] = __builtin_amdgcn_mfma_f32_16x16x32_f16(a1, B[q][2 * s + 1], acc[q], 0, 0, 0);
      }
      // remote slices as they arrive
#pragma unroll
      for (int j = 1; j < 4; j++) {
        const int ss = (s + j) & 3;
        int guard = 0;
        while (__hip_atomic_load(&flg[ss], __ATOMIC_RELAXED, __HIP_MEMORY_SCOPE_AGENT) < t) {
          __builtin_amdgcn_s_sleep(1);
          if (++guard > (1 << 26)) break;   // anti-hang bail
        }
        __builtin_amdgcn_fence(__ATOMIC_ACQUIRE, "agent");
        half8 a0 = *(const half8*)(hb + (2 * ss) * 32 + lg * 8);
        half8 a1 = *(const half8*)(hb + (2 * ss + 1) * 32 + lg * 8);
#pragma unroll
        for (int q = 0; q < 4; q++) acc[q] = __builtin_amdgcn_mfma_f32_16x16x32_f16(a0, B[q][2 * ss], acc[q], 0, 0, 0);
#pragma unroll
        for (int q = 0; q < 4; q++) acc[q] = __builtin_amdgcn_mfma_f32_16x16x32_f16(a1, B[q][2 * ss + 1], acc[q], 0, 0, 0);
      }
    }

    // gates + state update + stores; D-frag: row(b) = lg*4+rr, col(u) = l16
    unsigned short* hbw = hb_base + (size_t)(t & 1) * 64 * 256;
#pragma unroll
    for (int rr = 0; rr < 4; rr++) {
      const float zi = acc[0][rr], zf = acc[1][rr], zg = acc[2][rr], zo = acc[3][rr];
      const float cc = sigf(zf) * c[rr] + sigf(zi) * tanhf_(zg);
      c[rr] = cc;
      const float hh = sigf(zo) * tanhf_(cc);
      const int b = b0 + lg * 4 + rr;
      hbw[(size_t)b * 256 + u] = f2h(hh);
      if (LAYER == 1) {
        h1[(size_t)(tt * 64 + b) * 512 + d * 256 + u] = f2h(hh);
      } else {
        out[((size_t)b << 10 | tt) * 512 + d * 256 + u] = hh;
      }
    }

    __syncthreads();                       // all waves' stores drained (vmcnt 0)
    if (tid == 0) {
      __builtin_amdgcn_fence(__ATOMIC_RELEASE, "agent");   // L2 writeback for cross-XCD
      __hip_atomic_store(&flg[s], t + 1, __ATOMIC_RELAXED, __HIP_MEMORY_SCOPE_AGENT);
    }
  }
}

// LayerNorm over 512 features; one wave per row. f16 in/out, f32 math.
__global__ __launch_bounds__(256) void k_ln(
    const unsigned short* __restrict__ h1, const float* __restrict__ gamma,
    const float* __restrict__ beta, unsigned short* __restrict__ ln1) {
  const int tid = threadIdx.x, w = tid >> 6, l = tid & 63;
  const size_t row = (size_t)blockIdx.x * 4 + w;
  const unsigned short* src = h1 + row * 512 + l * 8;
  const ushort4v v0 = *(const ushort4v*)src;
  const ushort4v v1 = *(const ushort4v*)(src + 4);
  float xv[8] = {h2f(v0.x), h2f(v0.y), h2f(v0.z), h2f(v0.w),
                 h2f(v1.x), h2f(v1.y), h2f(v1.z), h2f(v1.w)};
  float sum = 0.f, ssq = 0.f;
#pragma unroll
  for (int i = 0; i < 8; i++) { sum += xv[i]; ssq += xv[i] * xv[i]; }
#pragma unroll
  for (int off = 32; off; off >>= 1) {
    sum += __shfl_xor(sum, off);
    ssq += __shfl_xor(ssq, off);
  }
  const float mu = sum * (1.f / 512.f);
  const float var = ssq * (1.f / 512.f) - mu * mu;
  const float rs = __builtin_amdgcn_rsqf(var + 1e-3f);
  const f32x4 g0 = *(const f32x4*)(gamma + l * 8);
  const f32x4 g1 = *(const f32x4*)(gamma + l * 8 + 4);
  const f32x4 e0 = *(const f32x4*)(beta + l * 8);
  const f32x4 e1 = *(const f32x4*)(beta + l * 8 + 4);
  float gg[8] = {g0.x, g0.y, g0.z, g0.w, g1.x, g1.y, g1.z, g1.w};
  float ee[8] = {e0.x, e0.y, e0.z, e0.w, e1.x, e1.y, e1.z, e1.w};
  unsigned short hh[8];
#pragma unroll
  for (int i = 0; i < 8; i++)
    hh[i] = f2h((xv[i] - mu) * rs * gg[i] + ee[i]);
  unsigned short* dst = ln1 + row * 512 + l * 8;
  *(ushort4v*)dst = (ushort4v){hh[0], hh[1], hh[2], hh[3]};
  *(ushort4v*)(dst + 4) = (ushort4v){hh[4], hh[5], hh[6], hh[7]};
}

extern "C" void kernel_launch(void* const* d_in, const int* in_sizes, int n_in,
                              void* d_out, int out_size, void* d_ws, size_t ws_size,
                              hipStream_t stream) {
  (void)in_sizes; (void)n_in; (void)out_size; (void)ws_size;
  const float* x     = (const float*)d_in[0];
  const float* W1f   = (const float*)d_in[1];
  const float* U1f   = (const float*)d_in[2];
  const float* b1f   = (const float*)d_in[3];
  const float* W1b   = (const float*)d_in[4];
  const float* U1b   = (const float*)d_in[5];
  const float* b1b   = (const float*)d_in[6];
  const float* gamma = (const float*)d_in[7];
  const float* beta  = (const float*)d_in[8];
  const float* W2f   = (const float*)d_in[9];
  const float* U2f   = (const float*)d_in[10];
  const float* b2f   = (const float*)d_in[11];
  const float* W2b   = (const float*)d_in[12];
  const float* U2b   = (const float*)d_in[13];
  const float* b2b   = (const float*)d_in[14];

  char* ws = (char*)d_ws;
  size_t ofs = 0;
  auto alloc = [&](size_t bytes) -> void* {
    void* p = ws + ofs;
    ofs += (bytes + 255) & ~(size_t)255;
    return p;
  };
  int* flags            = (int*)alloc(4096);                        // 64 ints (2 layers x 32)
  unsigned short* hbuf  = (unsigned short*)alloc((size_t)2*2*64*256*2);
  unsigned short* Wt1f  = (unsigned short*)alloc((size_t)1024*128*2);
  unsigned short* Wt1b  = (unsigned short*)alloc((size_t)1024*128*2);
  unsigned short* Ut1f  = (unsigned short*)alloc((size_t)1024*256*2);
  unsigned short* Ut1b  = (unsigned short*)alloc((size_t)1024*256*2);
  unsigned short* Ut2f  = (unsigned short*)alloc((size_t)1024*256*2);
  unsigned short* Ut2b  = (unsigned short*)alloc((size_t)1024*256*2);
  unsigned short* Wt2f  = (unsigned short*)alloc((size_t)1024*512*2);
  unsigned short* Wt2b  = (unsigned short*)alloc((size_t)1024*512*2);
  unsigned short* zxf   = (unsigned short*)alloc((size_t)1024*1024*64*2);  // 128MB
  unsigned short* zxb   = (unsigned short*)alloc((size_t)1024*1024*64*2);  // 128MB

  // d_out (128MB) doubles as scratch with time-disjoint lifetimes:
  //   xb (16MB, dead after zx1) -> h1 (64MB, dead after LN) ; ln1 at +64MB
  //   (dead after zx2); final f32 output overwrites everything in k_rec<2>.
  unsigned short* xb  = (unsigned short*)d_out;
  unsigned short* h1  = (unsigned short*)d_out;
  unsigned short* ln1 = (unsigned short*)d_out + (size_t)65536 * 512;

  k_init<<<1, 64, 0, stream>>>(flags);
  k_transpose<<<1024 * 128 / 256, 256, 0, stream>>>(W1f, Wt1f, 128);
  k_transpose<<<1024 * 128 / 256, 256, 0, stream>>>(W1b, Wt1b, 128);
  k_transpose<<<1024 * 256 / 256, 256, 0, stream>>>(U1f, Ut1f, 256);
  k_transpose<<<1024 * 256 / 256, 256, 0, stream>>>(U1b, Ut1b, 256);
  k_transpose<<<1024 * 512 / 256, 256, 0, stream>>>(W2f, Wt2f, 512);
  k_transpose<<<1024 * 512 / 256, 256, 0, stream>>>(W2b, Wt2b, 512);
  k_transpose<<<1024 * 256 / 256, 256, 0, stream>>>(U2f, Ut2f, 256);
  k_transpose<<<1024 * 256 / 256, 256, 0, stream>>>(U2b, Ut2b, 256);
  k_cvtx<<<8192, 256, 0, stream>>>(x, xb);

  dim3 zgrid(512, 8, 2);
  k_zx<128><<<zgrid, 256, 0, stream>>>(xb, Wt1f, Wt1b, b1f, b1b, zxf, zxb);
  k_rec<1><<<32, 256, 0, stream>>>(zxf, zxb, Ut1f, Ut1b, hbuf, flags, h1, nullptr);
  k_ln<<<65536 / 4, 256, 0, stream>>>(h1, gamma, beta, ln1);
  k_zx<512><<<zgrid, 256, 0, stream>>>(ln1, Wt2f, Wt2b, b2f, b2b, zxf, zxb);
  k_rec<2><<<32, 256, 0, stream>>>(zxf, zxb, Ut2f, Ut2b, hbuf, flags + 32, nullptr, (float*)d_out);
}

// Round 4
// 9647.334 us; speedup vs baseline: 1.6678x; 1.6678x over previous
//
#include <hip/hip_runtime.h>

// BiLSTM(128->2x256) -> LayerNorm(512) -> BiLSTM(512->2x256), B=64 T=1024.
// f16 MFMA inputs (11-bit mantissa, values tiny -> safe), f32 accum/cell.
// Recurrence: persistent 32-WG kernel (2 dir x 4 batch-group x 4 u-slice).
// Cross-WG h exchange is FENCE-FREE: h goes through L3 via sc0|sc1 (device-
// coherent) loads/stores; flags via relaxed agent atomics. No buffer_wbl2 /
// buffer_inv in the step loop (those made each step cost 7.5us in round 3).

typedef __attribute__((ext_vector_type(8))) _Float16 half8;    // f16x8 MFMA frag
typedef __attribute__((ext_vector_type(4))) float f32x4;       // MFMA acc
typedef __attribute__((ext_vector_type(4))) unsigned short ushort4v;
typedef __attribute__((ext_vector_type(2))) unsigned long long ull2;

#define LOG2E 1.4426950408889634f

static __device__ __forceinline__ unsigned short f2h(float f) {
  _Float16 h = (_Float16)f;
  return __builtin_bit_cast(unsigned short, h);
}
static __device__ __forceinline__ float h2f(unsigned short u) {
  _Float16 h = __builtin_bit_cast(_Float16, u);
  return (float)h;
}
static __device__ __forceinline__ float sigf(float x) {
  return __builtin_amdgcn_rcpf(1.f + __builtin_amdgcn_exp2f(-LOG2E * x));
}
static __device__ __forceinline__ float tanhf_(float x) {
  return 1.f - 2.f * __builtin_amdgcn_rcpf(__builtin_amdgcn_exp2f((2.f * LOG2E) * x) + 1.f);
}

// Device-coherent (L3 coherence point) access helpers: sc0|sc1 bypass L1/L2.
static __device__ __forceinline__ unsigned long long ld_b64_dev(const unsigned long long* p) {
  unsigned long long v;
  asm volatile("global_load_dwordx2 %0, %1, off sc0 sc1" : "=v"(v) : "v"(p));
  return v;
}
static __device__ __forceinline__ void st_b32_dev(unsigned* p, unsigned v) {
  asm volatile("global_store_dword %0, %1, off sc0 sc1" :: "v"(p), "v"(v) : "memory");
}

__global__ void k_init(int* flags) {
  if (threadIdx.x < 64) flags[threadIdx.x] = 0;
}

// out[c][k] = f16(in[k][c]); in is [K][1024] f32, out is [1024][K] f16.
__global__ void k_transpose(const float* __restrict__ in, unsigned short* __restrict__ out, int K) {
  int idx = blockIdx.x * 256 + threadIdx.x;   // idx = c*K + k
  int c = idx / K, k = idx - c * K;
  out[idx] = f2h(in[k * 1024 + c]);
}

// x [b][t][128] f32 -> xb [(t*64+b)][128] f16
__global__ void k_cvtx(const float* __restrict__ x, unsigned short* __restrict__ xb) {
  int i = blockIdx.x * 256 + threadIdx.x;
  int o = i * 4;
  int k = o & 127, row = o >> 7;            // row = t*64+b
  int b = row & 63, t = row >> 6;
  const f32x4 v = *(const f32x4*)(x + (size_t)((b << 10) + t) * 128 + k);
  ushort4v r;
  r.x = f2h(v.x); r.y = f2h(v.y); r.z = f2h(v.z); r.w = f2h(v.w);
  *(ushort4v*)(xb + o) = r;
}

// zx GEMM: A [65536 rows=(t*64+b)][K] f16 times Wt [1024][K] f16 (+bias)
// -> out [1024 t][1024 col][64 b] f16.  128x128 tiles, direct-global frags.
template<int K>
__global__ __launch_bounds__(256, 2) void k_zx(
    const unsigned short* __restrict__ A,
    const unsigned short* __restrict__ Wt_f, const unsigned short* __restrict__ Wt_b,
    const float* __restrict__ bias_f, const float* __restrict__ bias_b,
    unsigned short* __restrict__ out_f, unsigned short* __restrict__ out_b) {
  const int tid = threadIdx.x, w = tid >> 6, l = tid & 63;
  const int l16 = l & 15, lg = l >> 4;
  const int wm = w & 1, wn = w >> 1;
  const int rowbase = blockIdx.x * 128 + wm * 64;
  const int colbase = blockIdx.y * 128 + wn * 64;
  const unsigned short* Wt = blockIdx.z ? Wt_b : Wt_f;
  const float* bias = blockIdx.z ? bias_b : bias_f;
  unsigned short* out = blockIdx.z ? out_b : out_f;

  f32x4 acc[4][4];
#pragma unroll
  for (int nt = 0; nt < 4; nt++) {
    float bv = bias[colbase + nt * 16 + l16];
#pragma unroll
    for (int mt = 0; mt < 4; mt++) acc[mt][nt] = (f32x4){bv, bv, bv, bv};
  }

  for (int kf = 0; kf < K / 32; kf++) {
    const int ko = kf * 32 + lg * 8;
    half8 a[4], b[4];
#pragma unroll
    for (int mt = 0; mt < 4; mt++)
      a[mt] = *(const half8*)(A + (size_t)(rowbase + mt * 16 + l16) * K + ko);
#pragma unroll
    for (int nt = 0; nt < 4; nt++)
      b[nt] = *(const half8*)(Wt + (size_t)(colbase + nt * 16 + l16) * K + ko);
#pragma unroll
    for (int mt = 0; mt < 4; mt++)
#pragma unroll
      for (int nt = 0; nt < 4; nt++)
        acc[mt][nt] = __builtin_amdgcn_mfma_f32_16x16x32_f16(a[mt], b[nt], acc[mt][nt], 0, 0, 0);
  }

#pragma unroll
  for (int mt = 0; mt < 4; mt++) {
    const int rowchunk = rowbase + mt * 16;       // multiple of 16, within one t
    const int t = rowchunk >> 6;
    const int b0 = (rowchunk & 63) + lg * 4;
#pragma unroll
    for (int nt = 0; nt < 4; nt++) {
      const int c = colbase + nt * 16 + l16;
      ushort4v r;
      r.x = f2h(acc[mt][nt].x); r.y = f2h(acc[mt][nt].y);
      r.z = f2h(acc[mt][nt].z); r.w = f2h(acc[mt][nt].w);
      *(ushort4v*)(out + (((size_t)t << 10 | c) << 6) + b0) = r;
    }
  }
}

// Persistent recurrent kernel. 32 blocks: bid = s*8 + d*4 + g
//   s: u-slice (64 u each), d: direction, g: batch-group (16 batches).
// hbuf: [2d][4g][2 slot][16 b_local][256 u] f16, exchanged through L3.
template<int LAYER>
__global__ __launch_bounds__(256, 1) void k_rec(
    const unsigned short* __restrict__ zx_f, const unsigned short* __restrict__ zx_b,
    const unsigned short* __restrict__ Ut_f, const unsigned short* __restrict__ Ut_b,
    unsigned short* __restrict__ hbuf,
    int* __restrict__ flags,             // [2 dir][4 g][4 s]
    unsigned short* __restrict__ h1,     // LAYER==1: [(t*64+b)][512] f16
    float* __restrict__ out) {           // LAYER==2: [b][t][512] f32
  const int tid = threadIdx.x, w = tid >> 6, l = tid & 63;
  const int l16 = l & 15, lg = l >> 4;
  const int bid = blockIdx.x;
  const int s = bid >> 3, r5 = bid & 7, d = r5 >> 2, g = r5 & 3;
  const int b0 = g * 16;
  const int u = s * 64 + w * 16 + l16;   // this lane's u (col within slice block)

  const unsigned short* zx = d ? zx_b : zx_f;
  const unsigned short* Ut = d ? Ut_b : Ut_f;
  unsigned short* hg = hbuf + (size_t)(d * 4 + g) * 8192;   // group base (2 slots x 16 x 256)
  int* flg = flags + (d * 4 + g) * 4;

  // Recurrent weight fragments, resident in registers: B[q][kf], q = i/f/g/o.
  half8 B[4][8];
#pragma unroll
  for (int q = 0; q < 4; q++) {
    const unsigned short* colp = Ut + (size_t)(q * 256 + u) * 256;
#pragma unroll
    for (int kf = 0; kf < 8; kf++)
      B[q][kf] = *(const half8*)(colp + kf * 32 + lg * 8);
  }

  f32x4 c = (f32x4){0.f, 0.f, 0.f, 0.f};

  // prefetch zx for t=0
  ushort4v zq[4];
  {
    const int tt0 = d ? 1023 : 0;
#pragma unroll
    for (int q = 0; q < 4; q++)
      zq[q] = *(const ushort4v*)(zx + (((size_t)tt0 << 10 | (q * 256 + u)) << 6) + b0 + lg * 4);
  }

  for (int t = 0; t < 1024; t++) {
    const int tt = d ? 1023 - t : t;
    f32x4 acc[4];
#pragma unroll
    for (int q = 0; q < 4; q++)
      acc[q] = (f32x4){h2f(zq[q].x), h2f(zq[q].y), h2f(zq[q].z), h2f(zq[q].w)};

    unsigned long long ev[16];
    if (t > 0) {
      // wait for all 3 remote slices (own slice flag is trivially >= t)
#pragma unroll
      for (int j = 1; j < 4; j++) {
        const int ss = (s + j) & 3;
        int guard = 0;
        while (__hip_atomic_load(&flg[ss], __ATOMIC_RELAXED, __HIP_MEMORY_SCOPE_AGENT) < t) {
          __builtin_amdgcn_s_sleep(1);
          if (++guard > (1 << 26)) break;   // anti-hang bail
        }
      }
      // issue all 16 device-coherent 8B loads of h row l16 (full K=256)
      const unsigned long long* hr =
          (const unsigned long long*)(hg + ((t - 1) & 1) * 4096 + l16 * 256);
#pragma unroll
      for (int kb = 0; kb < 8; kb++) {
        ev[2 * kb]     = ld_b64_dev(hr + kb * 8 + lg * 2);
        ev[2 * kb + 1] = ld_b64_dev(hr + kb * 8 + lg * 2 + 1);
      }
      __builtin_amdgcn_sched_barrier(0);   // keep zq prefetch AFTER ev issues
    }

    if (t + 1 < 1024) {  // prefetch next step's zx (plain cached loads)
      const int tn = d ? tt - 1 : tt + 1;
#pragma unroll
      for (int q = 0; q < 4; q++)
        zq[q] = *(const ushort4v*)(zx + (((size_t)tn << 10 | (q * 256 + u)) << 6) + b0 + lg * 4);
    }

    if (t > 0) {
      // ev are the 16 oldest outstanding vmem ops; leave the 4 zq in flight.
      if (t + 1 < 1024) asm volatile("s_waitcnt vmcnt(4)" ::: "memory");
      else              asm volatile("s_waitcnt vmcnt(0)" ::: "memory");
      __builtin_amdgcn_sched_barrier(0);   // rule #18: no MFMA hoist above wait
#pragma unroll
      for (int kb = 0; kb < 8; kb++) {
        ull2 pr; pr.x = ev[2 * kb]; pr.y = ev[2 * kb + 1];
        half8 a = __builtin_bit_cast(half8, pr);
#pragma unroll
        for (int q = 0; q < 4; q++)
          acc[q] = __builtin_amdgcn_mfma_f32_16x16x32_f16(a, B[q][kb], acc[q], 0, 0, 0);
      }
    }

    // gates + state update; D-frag: row(b_local) = lg*4+rr, col(u) = l16
    unsigned short hb16[4];
#pragma unroll
    for (int rr = 0; rr < 4; rr++) {
      const float zi = acc[0][rr], zf = acc[1][rr], zg = acc[2][rr], zo = acc[3][rr];
      const float cc = sigf(zf) * c[rr] + sigf(zi) * tanhf_(zg);
      c[rr] = cc;
      const float hh = sigf(zo) * tanhf_(cc);
      hb16[rr] = f2h(hh);
      const int b = b0 + lg * 4 + rr;
      if (LAYER == 1) {
        h1[(size_t)(tt * 64 + b) * 512 + d * 256 + u] = hb16[rr];
      } else {
        out[((size_t)b << 10 | tt) * 512 + d * 256 + u] = hh;
      }
    }

    // publish h to hbuf (L3): pack lane-pairs (u, u+1) into 4B device stores
    {
      unsigned prt[4];
#pragma unroll
      for (int rr = 0; rr < 4; rr++)
        prt[rr] = (unsigned)__shfl_xor((int)(unsigned)hb16[rr], 1);
      const int odd = l16 & 1;
      const int rb = odd ? 2 : 0;
      unsigned* hbw32 = (unsigned*)(hg + (t & 1) * 4096);
#pragma unroll
      for (int k = 0; k < 2; k++) {
        const int rr = rb + k;
        const unsigned lo = odd ? prt[rr] : (unsigned)hb16[rr];
        const unsigned hi = odd ? (unsigned)hb16[rr] : prt[rr];
        const unsigned pk = (lo & 0xffffu) | (hi << 16);
        st_b32_dev(hbw32 + (lg * 4 + rr) * 128 + (u >> 1), pk);
      }
    }

    __syncthreads();   // drains vmcnt -> all sc0|sc1 stores are L3-visible
    if (tid == 0)
      __hip_atomic_store(&flg[s], t + 1, __ATOMIC_RELAXED, __HIP_MEMORY_SCOPE_AGENT);
  }
}

// LayerNorm over 512 features; one wave per row. f16 in/out, f32 math.
__global__ __launch_bounds__(256) void k_ln(
    const unsigned short* __restrict__ h1, const float* __restrict__ gamma,
    const float* __restrict__ beta, unsigned short* __restrict__ ln1) {
  const int tid = threadIdx.x, w = tid >> 6, l = tid & 63;
  const size_t row = (size_t)blockIdx.x * 4 + w;
  const unsigned short* src = h1 + row * 512 + l * 8;
  const ushort4v v0 = *(const ushort4v*)src;
  const ushort4v v1 = *(const ushort4v*)(src + 4);
  float xv[8] = {h2f(v0.x), h2f(v0.y), h2f(v0.z), h2f(v0.w),
                 h2f(v1.x), h2f(v1.y), h2f(v1.z), h2f(v1.w)};
  float sum = 0.f, ssq = 0.f;
#pragma unroll
  for (int i = 0; i < 8; i++) { sum += xv[i]; ssq += xv[i] * xv[i]; }
#pragma unroll
  for (int off = 32; off; off >>= 1) {
    sum += __shfl_xor(sum, off);
    ssq += __shfl_xor(ssq, off);
  }
  const float mu = sum * (1.f / 512.f);
  const float var = ssq * (1.f / 512.f) - mu * mu;
  const float rs = __builtin_amdgcn_rsqf(var + 1e-3f);
  const f32x4 g0 = *(const f32x4*)(gamma + l * 8);
  const f32x4 g1 = *(const f32x4*)(gamma + l * 8 + 4);
  const f32x4 e0 = *(const f32x4*)(beta + l * 8);
  const f32x4 e1 = *(const f32x4*)(beta + l * 8 + 4);
  float gg[8] = {g0.x, g0.y, g0.z, g0.w, g1.x, g1.y, g1.z, g1.w};
  float ee[8] = {e0.x, e0.y, e0.z, e0.w, e1.x, e1.y, e1.z, e1.w};
  unsigned short hh[8];
#pragma unroll
  for (int i = 0; i < 8; i++)
    hh[i] = f2h((xv[i] - mu) * rs * gg[i] + ee[i]);
  unsigned short* dst = ln1 + row * 512 + l * 8;
  *(ushort4v*)dst = (ushort4v){hh[0], hh[1], hh[2], hh[3]};
  *(ushort4v*)(dst + 4) = (ushort4v){hh[4], hh[5], hh[6], hh[7]};
}

extern "C" void kernel_launch(void* const* d_in, const int* in_sizes, int n_in,
                              void* d_out, int out_size, void* d_ws, size_t ws_size,
                              hipStream_t stream) {
  (void)in_sizes; (void)n_in; (void)out_size; (void)ws_size;
  const float* x     = (const float*)d_in[0];
  const float* W1f   = (const float*)d_in[1];
  const float* U1f   = (const float*)d_in[2];
  const float* b1f   = (const float*)d_in[3];
  const float* W1b   = (const float*)d_in[4];
  const float* U1b   = (const float*)d_in[5];
  const float* b1b   = (const float*)d_in[6];
  const float* gamma = (const float*)d_in[7];
  const float* beta  = (const float*)d_in[8];
  const float* W2f   = (const float*)d_in[9];
  const float* U2f   = (const float*)d_in[10];
  const float* b2f   = (const float*)d_in[11];
  const float* W2b   = (const float*)d_in[12];
  const float* U2b   = (const float*)d_in[13];
  const float* b2b   = (const float*)d_in[14];

  char* ws = (char*)d_ws;
  size_t ofs = 0;
  auto alloc = [&](size_t bytes) -> void* {
    void* p = ws + ofs;
    ofs += (bytes + 255) & ~(size_t)255;
    return p;
  };
  int* flags            = (int*)alloc(4096);                        // 64 ints (2 layers x 32)
  unsigned short* hbuf  = (unsigned short*)alloc((size_t)2*4*2*16*256*2);  // 256KB
  unsigned short* Wt1f  = (unsigned short*)alloc((size_t)1024*128*2);
  unsigned short* Wt1b  = (unsigned short*)alloc((size_t)1024*128*2);
  unsigned short* Ut1f  = (unsigned short*)alloc((size_t)1024*256*2);
  unsigned short* Ut1b  = (unsigned short*)alloc((size_t)1024*256*2);
  unsigned short* Ut2f  = (unsigned short*)alloc((size_t)1024*256*2);
  unsigned short* Ut2b  = (unsigned short*)alloc((size_t)1024*256*2);
  unsigned short* Wt2f  = (unsigned short*)alloc((size_t)1024*512*2);
  unsigned short* Wt2b  = (unsigned short*)alloc((size_t)1024*512*2);
  unsigned short* zxf   = (unsigned short*)alloc((size_t)1024*1024*64*2);  // 128MB
  unsigned short* zxb   = (unsigned short*)alloc((size_t)1024*1024*64*2);  // 128MB

  // d_out (128MB) doubles as scratch with time-disjoint lifetimes:
  //   xb (16MB, dead after zx1) -> h1 (64MB, dead after LN) ; ln1 at +64MB
  //   (dead after zx2); final f32 output overwrites everything in k_rec<2>.
  unsigned short* xb  = (unsigned short*)d_out;
  unsigned short* h1  = (unsigned short*)d_out;
  unsigned short* ln1 = (unsigned short*)d_out + (size_t)65536 * 512;

  k_init<<<1, 64, 0, stream>>>(flags);
  k_transpose<<<1024 * 128 / 256, 256, 0, stream>>>(W1f, Wt1f, 128);
  k_transpose<<<1024 * 128 / 256, 256, 0, stream>>>(W1b, Wt1b, 128);
  k_transpose<<<1024 * 256 / 256, 256, 0, stream>>>(U1f, Ut1f, 256);
  k_transpose<<<1024 * 256 / 256, 256, 0, stream>>>(U1b, Ut1b, 256);
  k_transpose<<<1024 * 512 / 256, 256, 0, stream>>>(W2f, Wt2f, 512);
  k_transpose<<<1024 * 512 / 256, 256, 0, stream>>>(W2b, Wt2b, 512);
  k_transpose<<<1024 * 256 / 256, 256, 0, stream>>>(U2f, Ut2f, 256);
  k_transpose<<<1024 * 256 / 256, 256, 0, stream>>>(U2b, Ut2b, 256);
  k_cvtx<<<8192, 256, 0, stream>>>(x, xb);

  dim3 zgrid(512, 8, 2);
  k_zx<128><<<zgrid, 256, 0, stream>>>(xb, Wt1f, Wt1b, b1f, b1b, zxf, zxb);
  k_rec<1><<<32, 256, 0, stream>>>(zxf, zxb, Ut1f, Ut1b, hbuf, flags, h1, nullptr);
  k_ln<<<65536 / 4, 256, 0, stream>>>(h1, gamma, beta, ln1);
  k_zx<512><<<zgrid, 256, 0, stream>>>(ln1, Wt2f, Wt2b, b2f, b2b, zxf, zxb);
  k_rec<2><<<32, 256, 0, stream>>>(zxf, zxb, Ut2f, Ut2b, hbuf, flags + 32, nullptr, (float*)d_out);
}

// Round 5
// 8043.688 us; speedup vs baseline: 2.0003x; 1.1994x over previous
//
#include <hip/hip_runtime.h>

// BiLSTM(128->2x256) -> LayerNorm(512) -> BiLSTM(512->2x256), B=64 T=1024.
// f16 MFMA inputs (11-bit mantissa, values tiny -> safe), f32 accum/cell.
// Recurrence: persistent 32-WG kernel (2 dir x 4 batch-group x 4 u-slice).
// Cross-WG h exchange is SENTINEL-BASED and barrier-free: h for step t goes
// to a fresh history slot (pre-filled 0xFFFFFFFF = packed f16 NaN pair,
// unreachable for finite h). Consumers spin on the DATA itself with
// device-coherent (sc0 sc1 -> L3) 16B loads. No flags, no __syncthreads,
// no store-drain-before-flag: one store->load L3 round trip per step.
// Layer 1's history IS the h1 output buffer (free); layer 2 uses 64MB of ws
// (falls back to the round-4 flag protocol if ws_size is too small).

typedef __attribute__((ext_vector_type(8))) _Float16 half8;    // f16x8 MFMA frag
typedef __attribute__((ext_vector_type(4))) float f32x4;       // MFMA acc
typedef __attribute__((ext_vector_type(4))) unsigned short ushort4v;
typedef __attribute__((ext_vector_type(4))) unsigned int uint4v;
typedef __attribute__((ext_vector_type(2))) unsigned long long ull2;

#define LOG2E 1.4426950408889634f
#define SENTW 0xFFFFFFFFu

static __device__ __forceinline__ unsigned short f2h(float f) {
  _Float16 h = (_Float16)f;
  return __builtin_bit_cast(unsigned short, h);
}
static __device__ __forceinline__ float h2f(unsigned short u) {
  _Float16 h = __builtin_bit_cast(_Float16, u);
  return (float)h;
}
static __device__ __forceinline__ float sigf(float x) {
  return __builtin_amdgcn_rcpf(1.f + __builtin_amdgcn_exp2f(-LOG2E * x));
}
static __device__ __forceinline__ float tanhf_(float x) {
  return 1.f - 2.f * __builtin_amdgcn_rcpf(__builtin_amdgcn_exp2f((2.f * LOG2E) * x) + 1.f);
}

// Device-coherent (L3 coherence point) access helpers: sc0|sc1 bypass L1/L2.
static __device__ __forceinline__ uint4v ld_b128_dev(const uint4v* p) {
  uint4v v;
  asm volatile("global_load_dwordx4 %0, %1, off sc0 sc1" : "=v"(v) : "v"(p));
  return v;
}
static __device__ __forceinline__ unsigned long long ld_b64_dev(const unsigned long long* p) {
  unsigned long long v;
  asm volatile("global_load_dwordx2 %0, %1, off sc0 sc1" : "=v"(v) : "v"(p));
  return v;
}
static __device__ __forceinline__ void st_b32_dev(unsigned* p, unsigned v) {
  asm volatile("global_store_dword %0, %1, off sc0 sc1" :: "v"(p), "v"(v) : "memory");
}

__global__ void k_init(int* flags) {
  if (threadIdx.x < 64) flags[threadIdx.x] = 0;
}

// fill n16 16-byte chunks with the sentinel pattern
__global__ void k_fill(uint4v* p, unsigned n16) {
  const uint4v v = (uint4v){SENTW, SENTW, SENTW, SENTW};
  for (unsigned i = blockIdx.x * 256 + threadIdx.x; i < n16; i += gridDim.x * 256)
    p[i] = v;
}

// out[c][k] = f16(in[k][c]); in is [K][1024] f32, out is [1024][K] f16.
__global__ void k_transpose(const float* __restrict__ in, unsigned short* __restrict__ out, int K) {
  int idx = blockIdx.x * 256 + threadIdx.x;   // idx = c*K + k
  int c = idx / K, k = idx - c * K;
  out[idx] = f2h(in[k * 1024 + c]);
}

// x [b][t][128] f32 -> xb [(t*64+b)][128] f16
__global__ void k_cvtx(const float* __restrict__ x, unsigned short* __restrict__ xb) {
  int i = blockIdx.x * 256 + threadIdx.x;
  int o = i * 4;
  int k = o & 127, row = o >> 7;            // row = t*64+b
  int b = row & 63, t = row >> 6;
  const f32x4 v = *(const f32x4*)(x + (size_t)((b << 10) + t) * 128 + k);
  ushort4v r;
  r.x = f2h(v.x); r.y = f2h(v.y); r.z = f2h(v.z); r.w = f2h(v.w);
  *(ushort4v*)(xb + o) = r;
}

// zx GEMM: A [65536 rows=(t*64+b)][K] f16 times Wt [1024][K] f16 (+bias)
// -> out [1024 t][1024 col][64 b] f16.  128x128 tiles, direct-global frags.
template<int K>
__global__ __launch_bounds__(256, 2) void k_zx(
    const unsigned short* __restrict__ A,
    const unsigned short* __restrict__ Wt_f, const unsigned short* __restrict__ Wt_b,
    const float* __restrict__ bias_f, const float* __restrict__ bias_b,
    unsigned short* __restrict__ out_f, unsigned short* __restrict__ out_b) {
  const int tid = threadIdx.x, w = tid >> 6, l = tid & 63;
  const int l16 = l & 15, lg = l >> 4;
  const int wm = w & 1, wn = w >> 1;
  const int rowbase = blockIdx.x * 128 + wm * 64;
  const int colbase = blockIdx.y * 128 + wn * 64;
  const unsigned short* Wt = blockIdx.z ? Wt_b : Wt_f;
  const float* bias = blockIdx.z ? bias_b : bias_f;
  unsigned short* out = blockIdx.z ? out_b : out_f;

  f32x4 acc[4][4];
#pragma unroll
  for (int nt = 0; nt < 4; nt++) {
    float bv = bias[colbase + nt * 16 + l16];
#pragma unroll
    for (int mt = 0; mt < 4; mt++) acc[mt][nt] = (f32x4){bv, bv, bv, bv};
  }

  for (int kf = 0; kf < K / 32; kf++) {
    const int ko = kf * 32 + lg * 8;
    half8 a[4], b[4];
#pragma unroll
    for (int mt = 0; mt < 4; mt++)
      a[mt] = *(const half8*)(A + (size_t)(rowbase + mt * 16 + l16) * K + ko);
#pragma unroll
    for (int nt = 0; nt < 4; nt++)
      b[nt] = *(const half8*)(Wt + (size_t)(colbase + nt * 16 + l16) * K + ko);
#pragma unroll
    for (int mt = 0; mt < 4; mt++)
#pragma unroll
      for (int nt = 0; nt < 4; nt++)
        acc[mt][nt] = __builtin_amdgcn_mfma_f32_16x16x32_f16(a[mt], b[nt], acc[mt][nt], 0, 0, 0);
  }

#pragma unroll
  for (int mt = 0; mt < 4; mt++) {
    const int rowchunk = rowbase + mt * 16;       // multiple of 16, within one t
    const int t = rowchunk >> 6;
    const int b0 = (rowchunk & 63) + lg * 4;
#pragma unroll
    for (int nt = 0; nt < 4; nt++) {
      const int c = colbase + nt * 16 + l16;
      ushort4v r;
      r.x = f2h(acc[mt][nt].x); r.y = f2h(acc[mt][nt].y);
      r.z = f2h(acc[mt][nt].z); r.w = f2h(acc[mt][nt].w);
      *(ushort4v*)(out + (((size_t)t << 10 | c) << 6) + b0) = r;
    }
  }
}

// Persistent recurrent kernel. 32 blocks: bid = s*8 + d*4 + g
//   s: u-slice (64 u each), d: direction, g: batch-group (16 batches).
// SENT exchange layouts (f16, device-coherent):
//   LAYER1: hist = h1 [(tt*64+b)][512], col base d*256 (doubles as output)
//   LAYER2: hist = hh2 [((t*2+d)*64+b)][256]           (step-indexed)
template<int LAYER, bool SENT>
__global__ __launch_bounds__(256, 1) void k_rec(
    const unsigned short* __restrict__ zx_f, const unsigned short* __restrict__ zx_b,
    const unsigned short* __restrict__ Ut_f, const unsigned short* __restrict__ Ut_b,
    unsigned short* __restrict__ hist,   // SENT exchange buffer (see above)
    unsigned short* __restrict__ hbuf,   // !SENT: [2d][4g][2 slot][16 b][256 u]
    int* __restrict__ flags,             // !SENT: [2 dir][4 g][4 s]
    unsigned short* __restrict__ h1,     // LAYER==1 non-hist output path (unused if SENT)
    float* __restrict__ out) {           // LAYER==2: [b][t][512] f32
  const int tid = threadIdx.x, w = tid >> 6, l = tid & 63;
  const int l16 = l & 15, lg = l >> 4;
  const int bid = blockIdx.x;
  const int s = bid >> 3, r5 = bid & 7, d = r5 >> 2, g = r5 & 3;
  const int b0 = g * 16;
  const int u = s * 64 + w * 16 + l16;   // this lane's u (col within slice block)

  const unsigned short* zx = d ? zx_b : zx_f;
  const unsigned short* Ut = d ? Ut_b : Ut_f;
  unsigned short* hg = hbuf ? hbuf + (size_t)(d * 4 + g) * 8192 : nullptr;
  int* flg = flags ? flags + (d * 4 + g) * 4 : nullptr;

  // Recurrent weight fragments, resident in registers: B[q][kf], q = i/f/g/o.
  half8 B[4][8];
#pragma unroll
  for (int q = 0; q < 4; q++) {
    const unsigned short* colp = Ut + (size_t)(q * 256 + u) * 256;
#pragma unroll
    for (int kf = 0; kf < 8; kf++)
      B[q][kf] = *(const half8*)(colp + kf * 32 + lg * 8);
  }

  f32x4 c = (f32x4){0.f, 0.f, 0.f, 0.f};

  // prefetch zx for t=0
  ushort4v zq[4];
  {
    const int tt0 = d ? 1023 : 0;
#pragma unroll
    for (int q = 0; q < 4; q++)
      zq[q] = *(const ushort4v*)(zx + (((size_t)tt0 << 10 | (q * 256 + u)) << 6) + b0 + lg * 4);
  }

  for (int t = 0; t < 1024; t++) {
    const int tt = d ? 1023 - t : t;
    f32x4 acc[4];
#pragma unroll
    for (int q = 0; q < 4; q++)
      acc[q] = (f32x4){h2f(zq[q].x), h2f(zq[q].y), h2f(zq[q].z), h2f(zq[q].w)};

    if (t + 1 < 1024) {  // prefetch next step's zx; completes during the h spin
      const int tn = d ? tt - 1 : tt + 1;
#pragma unroll
      for (int q = 0; q < 4; q++)
        zq[q] = *(const ushort4v*)(zx + (((size_t)tn << 10 | (q * 256 + u)) << 6) + b0 + lg * 4);
    }

    if (t > 0) {
      if constexpr (SENT) {
        // ---- sentinel consume: spin directly on h(t-1) data in L3 ----
        const uint4v* rowp;
        if constexpr (LAYER == 1) {
          const int tp = d ? tt + 1 : tt - 1;     // time index of step t-1
          rowp = (const uint4v*)(hist + ((size_t)tp * 64 + b0 + l16) * 512 + d * 256);
        } else {
          rowp = (const uint4v*)(hist + (((size_t)(t - 1) * 2 + d) * 64 + b0 + l16) * 256);
        }
        uint4v ev4[8];
        int tries = 0;
        while (true) {
#pragma unroll
          for (int kb = 0; kb < 8; kb++) ev4[kb] = ld_b128_dev(rowp + kb * 4 + lg);
          asm volatile("s_waitcnt vmcnt(0)" ::: "memory");
          bool ok = true;
#pragma unroll
          for (int kb = 0; kb < 8; kb++)
            ok = ok && ev4[kb].x != SENTW && ev4[kb].y != SENTW &&
                 ev4[kb].z != SENTW && ev4[kb].w != SENTW;
          if (__all(ok)) break;
          if (++tries > (1 << 16)) break;          // anti-hang bail
          __builtin_amdgcn_s_sleep(1);
        }
        __builtin_amdgcn_sched_barrier(0);         // rule #18: no MFMA hoist
#pragma unroll
        for (int kb = 0; kb < 8; kb++) {
          half8 a = __builtin_bit_cast(half8, ev4[kb]);
#pragma unroll
          for (int q = 0; q < 4; q++)
            acc[q] = __builtin_amdgcn_mfma_f32_16x16x32_f16(a, B[q][kb], acc[q], 0, 0, 0);
        }
      } else {
        // ---- legacy flag-based consume (round-4 verified path) ----
#pragma unroll
        for (int j = 1; j < 4; j++) {
          const int ss = (s + j) & 3;
          int guard = 0;
          while (__hip_atomic_load(&flg[ss], __ATOMIC_RELAXED, __HIP_MEMORY_SCOPE_AGENT) < t) {
            __builtin_amdgcn_s_sleep(1);
            if (++guard > (1 << 26)) break;
          }
        }
        unsigned long long ev[16];
        const unsigned long long* hr =
            (const unsigned long long*)(hg + ((t - 1) & 1) * 4096 + l16 * 256);
#pragma unroll
        for (int kb = 0; kb < 8; kb++) {
          ev[2 * kb]     = ld_b64_dev(hr + kb * 8 + lg * 2);
          ev[2 * kb + 1] = ld_b64_dev(hr + kb * 8 + lg * 2 + 1);
        }
        asm volatile("s_waitcnt vmcnt(0)" ::: "memory");
        __builtin_amdgcn_sched_barrier(0);
#pragma unroll
        for (int kb = 0; kb < 8; kb++) {
          ull2 pr; pr.x = ev[2 * kb]; pr.y = ev[2 * kb + 1];
          half8 a = __builtin_bit_cast(half8, pr);
#pragma unroll
          for (int q = 0; q < 4; q++)
            acc[q] = __builtin_amdgcn_mfma_f32_16x16x32_f16(a, B[q][kb], acc[q], 0, 0, 0);
        }
      }
    }

    // gates + state update; D-frag: row(b_local) = lg*4+rr, col(u) = l16
    unsigned short hb16[4];
    float hf[4];
#pragma unroll
    for (int rr = 0; rr < 4; rr++) {
      const float zi = acc[0][rr], zf = acc[1][rr], zg = acc[2][rr], zo = acc[3][rr];
      const float cc = sigf(zf) * c[rr] + sigf(zi) * tanhf_(zg);
      c[rr] = cc;
      hf[rr] = sigf(zo) * tanhf_(cc);
      hb16[rr] = f2h(hf[rr]);
    }

    // publish h: pack lane-pairs (u even, u odd) into 4B device stores
    {
      unsigned prt[4];
#pragma unroll
      for (int rr = 0; rr < 4; rr++)
        prt[rr] = (unsigned)__shfl_xor((int)(unsigned)hb16[rr], 1);
      const int odd = l16 & 1;
      const int rb = odd ? 2 : 0;
      const int ue = u & ~1;
#pragma unroll
      for (int k = 0; k < 2; k++) {
        const int rr = rb + k;
        const int b = b0 + lg * 4 + rr;
        const unsigned lo = odd ? prt[rr] : (unsigned)hb16[rr];
        const unsigned hi = odd ? (unsigned)hb16[rr] : prt[rr];
        const unsigned pk = (lo & 0xffffu) | (hi << 16);
        if constexpr (SENT) {
          size_t widx;
          if constexpr (LAYER == 1)
            widx = (((size_t)tt * 64 + b) * 512 + d * 256 + ue) >> 1;
          else
            widx = ((((size_t)t * 2 + d) * 64 + b) * 256 + ue) >> 1;
          st_b32_dev((unsigned*)hist + widx, pk);
        } else {
          st_b32_dev((unsigned*)(hg + (t & 1) * 4096) + (b - b0) * 128 + (ue >> 1), pk);
        }
      }
    }

    // non-exchange outputs
#pragma unroll
    for (int rr = 0; rr < 4; rr++) {
      const int b = b0 + lg * 4 + rr;
      if (LAYER == 1 && !SENT) h1[(size_t)(tt * 64 + b) * 512 + d * 256 + u] = hb16[rr];
      if (LAYER == 2) out[((size_t)b << 10 | tt) * 512 + d * 256 + u] = hf[rr];
    }

    if constexpr (!SENT) {
      __syncthreads();   // drains vmcnt -> all sc0|sc1 stores are L3-visible
      if (tid == 0)
        __hip_atomic_store(&flg[s], t + 1, __ATOMIC_RELAXED, __HIP_MEMORY_SCOPE_AGENT);
    }
  }
}

// LayerNorm over 512 features; one wave per row. f16 in/out, f32 math.
__global__ __launch_bounds__(256) void k_ln(
    const unsigned short* __restrict__ h1, const float* __restrict__ gamma,
    const float* __restrict__ beta, unsigned short* __restrict__ ln1) {
  const int tid = threadIdx.x, w = tid >> 6, l = tid & 63;
  const size_t row = (size_t)blockIdx.x * 4 + w;
  const unsigned short* src = h1 + row * 512 + l * 8;
  const ushort4v v0 = *(const ushort4v*)src;
  const ushort4v v1 = *(const ushort4v*)(src + 4);
  float xv[8] = {h2f(v0.x), h2f(v0.y), h2f(v0.z), h2f(v0.w),
                 h2f(v1.x), h2f(v1.y), h2f(v1.z), h2f(v1.w)};
  float sum = 0.f, ssq = 0.f;
#pragma unroll
  for (int i = 0; i < 8; i++) { sum += xv[i]; ssq += xv[i] * xv[i]; }
#pragma unroll
  for (int off = 32; off; off >>= 1) {
    sum += __shfl_xor(sum, off);
    ssq += __shfl_xor(ssq, off);
  }
  const float mu = sum * (1.f / 512.f);
  const float var = ssq * (1.f / 512.f) - mu * mu;
  const float rs = __builtin_amdgcn_rsqf(var + 1e-3f);
  const f32x4 g0 = *(const f32x4*)(gamma + l * 8);
  const f32x4 g1 = *(const f32x4*)(gamma + l * 8 + 4);
  const f32x4 e0 = *(const f32x4*)(beta + l * 8);
  const f32x4 e1 = *(const f32x4*)(beta + l * 8 + 4);
  float gg[8] = {g0.x, g0.y, g0.z, g0.w, g1.x, g1.y, g1.z, g1.w};
  float ee[8] = {e0.x, e0.y, e0.z, e0.w, e1.x, e1.y, e1.z, e1.w};
  unsigned short hh[8];
#pragma unroll
  for (int i = 0; i < 8; i++)
    hh[i] = f2h((xv[i] - mu) * rs * gg[i] + ee[i]);
  unsigned short* dst = ln1 + row * 512 + l * 8;
  *(ushort4v*)dst = (ushort4v){hh[0], hh[1], hh[2], hh[3]};
  *(ushort4v*)(dst + 4) = (ushort4v){hh[4], hh[5], hh[6], hh[7]};
}

extern "C" void kernel_launch(void* const* d_in, const int* in_sizes, int n_in,
                              void* d_out, int out_size, void* d_ws, size_t ws_size,
                              hipStream_t stream) {
  (void)in_sizes; (void)n_in; (void)out_size;
  const float* x     = (const float*)d_in[0];
  const float* W1f   = (const float*)d_in[1];
  const float* U1f   = (const float*)d_in[2];
  const float* b1f   = (const float*)d_in[3];
  const float* W1b   = (const float*)d_in[4];
  const float* U1b   = (const float*)d_in[5];
  const float* b1b   = (const float*)d_in[6];
  const float* gamma = (const float*)d_in[7];
  const float* beta  = (const float*)d_in[8];
  const float* W2f   = (const float*)d_in[9];
  const float* U2f   = (const float*)d_in[10];
  const float* b2f   = (const float*)d_in[11];
  const float* W2b   = (const float*)d_in[12];
  const float* U2b   = (const float*)d_in[13];
  const float* b2b   = (const float*)d_in[14];

  char* ws = (char*)d_ws;
  size_t ofs = 0;
  auto alloc = [&](size_t bytes) -> void* {
    void* p = ws + ofs;
    ofs += (bytes + 255) & ~(size_t)255;
    return p;
  };
  int* flags            = (int*)alloc(4096);
  unsigned short* hbuf  = (unsigned short*)alloc((size_t)2*4*2*16*256*2);  // 256KB
  unsigned short* Wt1f  = (unsigned short*)alloc((size_t)1024*128*2);
  unsigned short* Wt1b  = (unsigned short*)alloc((size_t)1024*128*2);
  unsigned short* Ut1f  = (unsigned short*)alloc((size_t)1024*256*2);
  unsigned short* Ut1b  = (unsigned short*)alloc((size_t)1024*256*2);
  unsigned short* Ut2f  = (unsigned short*)alloc((size_t)1024*256*2);
  unsigned short* Ut2b  = (unsigned short*)alloc((size_t)1024*256*2);
  unsigned short* Wt2f  = (unsigned short*)alloc((size_t)1024*512*2);
  unsigned short* Wt2b  = (unsigned short*)alloc((size_t)1024*512*2);
  unsigned short* zxf   = (unsigned short*)alloc((size_t)1024*1024*64*2);  // 128MB
  unsigned short* zxb   = (unsigned short*)alloc((size_t)1024*1024*64*2);  // 128MB

  const size_t HH2_BYTES = (size_t)1024 * 2 * 64 * 256 * 2;   // 64MB
  const bool sent2 = ws_size >= ofs + HH2_BYTES;
  unsigned short* hh2 = sent2 ? (unsigned short*)alloc(HH2_BYTES) : nullptr;

  // d_out (128MB) doubles as scratch with time-disjoint lifetimes:
  //   xb (16MB, dead after zx1) -> h1 (64MB, sentinel-filled, exchange+output
  //   of k_rec<1>, dead after LN) ; ln1 at +64MB (dead after zx2); final f32
  //   output overwrites everything in k_rec<2>.
  unsigned short* xb  = (unsigned short*)d_out;
  unsigned short* h1  = (unsigned short*)d_out;
  unsigned short* ln1 = (unsigned short*)d_out + (size_t)65536 * 512;

  k_init<<<1, 64, 0, stream>>>(flags);
  k_transpose<<<1024 * 128 / 256, 256, 0, stream>>>(W1f, Wt1f, 128);
  k_transpose<<<1024 * 128 / 256, 256, 0, stream>>>(W1b, Wt1b, 128);
  k_transpose<<<1024 * 256 / 256, 256, 0, stream>>>(U1f, Ut1f, 256);
  k_transpose<<<1024 * 256 / 256, 256, 0, stream>>>(U1b, Ut1b, 256);
  k_transpose<<<1024 * 512 / 256, 256, 0, stream>>>(W2f, Wt2f, 512);
  k_transpose<<<1024 * 512 / 256, 256, 0, stream>>>(W2b, Wt2b, 512);
  k_transpose<<<1024 * 256 / 256, 256, 0, stream>>>(U2f, Ut2f, 256);
  k_transpose<<<1024 * 256 / 256, 256, 0, stream>>>(U2b, Ut2b, 256);
  k_cvtx<<<8192, 256, 0, stream>>>(x, xb);

  dim3 zgrid(512, 8, 2);
  k_zx<128><<<zgrid, 256, 0, stream>>>(xb, Wt1f, Wt1b, b1f, b1b, zxf, zxb);
  // sentinel-fill h1 region (xb is dead now), then barrier-free recurrence
  k_fill<<<2048, 256, 0, stream>>>((uint4v*)h1, 65536u * 512u / 8u);
  k_rec<1, true><<<32, 256, 0, stream>>>(zxf, zxb, Ut1f, Ut1b, h1, nullptr, nullptr, nullptr, nullptr);
  k_ln<<<65536 / 4, 256, 0, stream>>>(h1, gamma, beta, ln1);
  k_zx<512><<<zgrid, 256, 0, stream>>>(ln1, Wt2f, Wt2b, b2f, b2b, zxf, zxb);
  if (sent2) {
    k_fill<<<2048, 256, 0, stream>>>((uint4v*)hh2, (unsigned)(HH2_BYTES / 16));
    k_rec<2, true><<<32, 256, 0, stream>>>(zxf, zxb, Ut2f, Ut2b, hh2, nullptr, nullptr, nullptr, (float*)d_out);
  } else {
    k_rec<2, false><<<32, 256, 0, stream>>>(zxf, zxb, Ut2f, Ut2b, nullptr, hbuf, flags + 32, nullptr, (float*)d_out);
  }
}

// Round 6
// 5705.375 us; speedup vs baseline: 2.8201x; 1.4098x over previous
//
#include <hip/hip_runtime.h>

// BiLSTM(128->2x256) -> LayerNorm(512) -> BiLSTM(512->2x256), B=64 T=1024.
// f16 MFMA inputs, f32 accum/cell. Recurrence: 16 persistent WGs x 512 thr
// = (2 dir x 4 batch-group x 2 u-half). Each WG holds HALF of U(dir) in
// registers (128 VGPR/wave), computes its u-half for 16 batches. Per step:
// own-half h(t-1) comes from LDS (raw s_barrier + lgkmcnt, no vmcnt drain);
// partner half via ONE sentinel-polled device-coherent (sc0 sc1 -> L3) read,
// issued early and overlapped with own-half MFMA. zq prefetch issued AFTER
// the poll so vmcnt(0) covers only the 4 partner loads.

typedef __attribute__((ext_vector_type(8))) _Float16 half8;    // f16x8 MFMA frag
typedef __attribute__((ext_vector_type(4))) float f32x4;       // MFMA acc
typedef __attribute__((ext_vector_type(4))) unsigned short ushort4v;
typedef __attribute__((ext_vector_type(4))) unsigned int uint4v;

#define LOG2E 1.4426950408889634f
#define SENTW 0xFFFFFFFFu

static __device__ __forceinline__ unsigned short f2h(float f) {
  _Float16 h = (_Float16)f;
  return __builtin_bit_cast(unsigned short, h);
}
static __device__ __forceinline__ float h2f(unsigned short u) {
  _Float16 h = __builtin_bit_cast(_Float16, u);
  return (float)h;
}
static __device__ __forceinline__ float sigf(float x) {
  return __builtin_amdgcn_rcpf(1.f + __builtin_amdgcn_exp2f(-LOG2E * x));
}
static __device__ __forceinline__ float tanhf_(float x) {
  return 1.f - 2.f * __builtin_amdgcn_rcpf(__builtin_amdgcn_exp2f((2.f * LOG2E) * x) + 1.f);
}

// Device-coherent (L3 coherence point) access helpers: sc0|sc1 bypass L1/L2.
static __device__ __forceinline__ uint4v ld_b128_dev(const uint4v* p) {
  uint4v v;
  asm volatile("global_load_dwordx4 %0, %1, off sc0 sc1" : "=v"(v) : "v"(p));
  return v;
}
static __device__ __forceinline__ void st_b32_dev(unsigned* p, unsigned v) {
  asm volatile("global_store_dword %0, %1, off sc0 sc1" :: "v"(p), "v"(v) : "memory");
}

// fill n16 16-byte chunks with the sentinel pattern
__global__ void k_fill(uint4v* p, unsigned n16) {
  const uint4v v = (uint4v){SENTW, SENTW, SENTW, SENTW};
  for (unsigned i = blockIdx.x * 256 + threadIdx.x; i < n16; i += gridDim.x * 256)
    p[i] = v;
}

// out[c][k] = f16(in[k][c]); in is [K][1024] f32, out is [1024][K] f16.
__global__ void k_transpose(const float* __restrict__ in, unsigned short* __restrict__ out, int K) {
  int idx = blockIdx.x * 256 + threadIdx.x;   // idx = c*K + k
  int c = idx / K, k = idx - c * K;
  out[idx] = f2h(in[k * 1024 + c]);
}

// x [b][t][128] f32 -> xb [(t*64+b)][128] f16
__global__ void k_cvtx(const float* __restrict__ x, unsigned short* __restrict__ xb) {
  int i = blockIdx.x * 256 + threadIdx.x;
  int o = i * 4;
  int k = o & 127, row = o >> 7;            // row = t*64+b
  int b = row & 63, t = row >> 6;
  const f32x4 v = *(const f32x4*)(x + (size_t)((b << 10) + t) * 128 + k);
  ushort4v r;
  r.x = f2h(v.x); r.y = f2h(v.y); r.z = f2h(v.z); r.w = f2h(v.w);
  *(ushort4v*)(xb + o) = r;
}

// zx GEMM: A [65536 rows=(t*64+b)][K] f16 times Wt [1024][K] f16 (+bias)
// -> out [1024 t][1024 col][64 b] f16.  128x128 tiles, direct-global frags.
template<int K>
__global__ __launch_bounds__(256, 2) void k_zx(
    const unsigned short* __restrict__ A,
    const unsigned short* __restrict__ Wt_f, const unsigned short* __restrict__ Wt_b,
    const float* __restrict__ bias_f, const float* __restrict__ bias_b,
    unsigned short* __restrict__ out_f, unsigned short* __restrict__ out_b) {
  const int tid = threadIdx.x, w = tid >> 6, l = tid & 63;
  const int l16 = l & 15, lg = l >> 4;
  const int wm = w & 1, wn = w >> 1;
  const int rowbase = blockIdx.x * 128 + wm * 64;
  const int colbase = blockIdx.y * 128 + wn * 64;
  const unsigned short* Wt = blockIdx.z ? Wt_b : Wt_f;
  const float* bias = blockIdx.z ? bias_b : bias_f;
  unsigned short* out = blockIdx.z ? out_b : out_f;

  f32x4 acc[4][4];
#pragma unroll
  for (int nt = 0; nt < 4; nt++) {
    float bv = bias[colbase + nt * 16 + l16];
#pragma unroll
    for (int mt = 0; mt < 4; mt++) acc[mt][nt] = (f32x4){bv, bv, bv, bv};
  }

  for (int kf = 0; kf < K / 32; kf++) {
    const int ko = kf * 32 + lg * 8;
    half8 a[4], b[4];
#pragma unroll
    for (int mt = 0; mt < 4; mt++)
      a[mt] = *(const half8*)(A + (size_t)(rowbase + mt * 16 + l16) * K + ko);
#pragma unroll
    for (int nt = 0; nt < 4; nt++)
      b[nt] = *(const half8*)(Wt + (size_t)(colbase + nt * 16 + l16) * K + ko);
#pragma unroll
    for (int mt = 0; mt < 4; mt++)
#pragma unroll
      for (int nt = 0; nt < 4; nt++)
        acc[mt][nt] = __builtin_amdgcn_mfma_f32_16x16x32_f16(a[mt], b[nt], acc[mt][nt], 0, 0, 0);
  }

#pragma unroll
  for (int mt = 0; mt < 4; mt++) {
    const int rowchunk = rowbase + mt * 16;       // multiple of 16, within one t
    const int t = rowchunk >> 6;
    const int b0 = (rowchunk & 63) + lg * 4;
#pragma unroll
    for (int nt = 0; nt < 4; nt++) {
      const int c = colbase + nt * 16 + l16;
      ushort4v r;
      r.x = f2h(acc[mt][nt].x); r.y = f2h(acc[mt][nt].y);
      r.z = f2h(acc[mt][nt].z); r.w = f2h(acc[mt][nt].w);
      *(ushort4v*)(out + (((size_t)t << 10 | c) << 6) + b0) = r;
    }
  }
}

// Persistent recurrent kernel. 16 blocks x 512 threads: bid = d*8 + g*2 + half
//   d: direction, g: batch-group (16 b), half: u-half (128 u).
// Exchange layouts (f16, device-coherent):
//   LAYER1: exch = h1 [(tt*64+b)][512], col d*256+u (doubles as LN input)
//   LAYER2: exch = hist [t][d][g][half][16 b][128 u]
template<int LAYER>
__global__ __launch_bounds__(512, 2) void k_rec2(
    const unsigned short* __restrict__ zx_f, const unsigned short* __restrict__ zx_b,
    const unsigned short* __restrict__ Ut_f, const unsigned short* __restrict__ Ut_b,
    unsigned short* __restrict__ exch,
    float* __restrict__ out) {           // LAYER==2: [b][t][512] f32
  const int tid = threadIdx.x, wv = tid >> 6, l = tid & 63;
  const int l16 = l & 15, lg = l >> 4;
  const int bid = blockIdx.x;
  const int d = bid >> 3, g = (bid >> 1) & 3, half = bid & 1;
  const int b0 = g * 16;
  const int ug = half * 128 + wv * 16 + l16;   // this lane's u in [0,256)

  const unsigned short* zx = d ? zx_b : zx_f;
  const unsigned short* Ut = d ? Ut_b : Ut_f;

  // own-half h double-buffer in LDS: [slot][16 b][128 u], XOR-swizzled rows
  __shared__ unsigned short hlds[2 * 16 * 128];

  // B[q][j]: j 0..3 = OWN kf (half*4+j), j 4..7 = REMOTE kf ((half^1)*4+j-4)
  // (compile-time j indexing -> stays in registers, rule #20)
  half8 B[4][8];
#pragma unroll
  for (int j = 0; j < 8; j++) {
    const int kf = (j < 4) ? (half * 4 + j) : ((half ^ 1) * 4 + (j - 4));
#pragma unroll
    for (int q = 0; q < 4; q++)
      B[q][j] = *(const half8*)(Ut + (size_t)(q * 256 + ug) * 256 + kf * 32 + lg * 8);
  }

  f32x4 c = (f32x4){0.f, 0.f, 0.f, 0.f};

  ushort4v zq[4];
  {
    const int t0 = d ? 1023 : 0;
#pragma unroll
    for (int q = 0; q < 4; q++)
      zq[q] = *(const ushort4v*)(zx + (((size_t)t0 << 10 | (q * 256 + ug)) << 6) + b0 + lg * 4);
  }

  for (int t = 0; t < 1024; t++) {
    const int tt = d ? 1023 - t : t;
    f32x4 acc[4];
#pragma unroll
    for (int q = 0; q < 4; q++)
      acc[q] = (f32x4){h2f(zq[q].x), h2f(zq[q].y), h2f(zq[q].z), h2f(zq[q].w)};

    if (t > 0) {
      // partner-half poll address (row = batch l16, 4x16B chunks by kfo,lg)
      const uint4v* rowp;
      if constexpr (LAYER == 1) {
        const int tp = d ? tt + 1 : tt - 1;   // time index of step t-1
        rowp = (const uint4v*)(exch + ((size_t)tp * 64 + b0 + l16) * 512 + d * 256 + (half ^ 1) * 128);
      } else {
        rowp = (const uint4v*)(exch + (((((size_t)(t - 1) * 2 + d) * 4 + g) * 2 + (half ^ 1)) * 2048)
                               + (size_t)l16 * 128);
      }
      uint4v pv0 = ld_b128_dev(rowp + 0 + lg);
      uint4v pv1 = ld_b128_dev(rowp + 4 + lg);
      uint4v pv2 = ld_b128_dev(rowp + 8 + lg);
      uint4v pv3 = ld_b128_dev(rowp + 12 + lg);

      // own-half h(t-1) from LDS (lgkmcnt path, overlaps the L3 round trip)
      half8 ha[4];
#pragma unroll
      for (int kfo = 0; kfo < 4; kfo++) {
        const int idx = ((l16 * 128 + kfo * 32 + lg * 8) ^ ((l16 & 7) << 3)) + ((t - 1) & 1) * 2048;
        ha[kfo] = *(const half8*)&hlds[idx];
      }
#pragma unroll
      for (int kfo = 0; kfo < 4; kfo++)
#pragma unroll
        for (int q = 0; q < 4; q++)
          acc[q] = __builtin_amdgcn_mfma_f32_16x16x32_f16(ha[kfo], B[q][kfo], acc[q], 0, 0, 0);

      // sentinel poll on the partner data (only these 4 loads are in vmcnt)
      int tries = 0;
      while (true) {
        asm volatile("s_waitcnt vmcnt(0)" ::: "memory");
        __builtin_amdgcn_sched_barrier(0);
        bool ok = pv0.x != SENTW && pv0.y != SENTW && pv0.z != SENTW && pv0.w != SENTW &&
                  pv1.x != SENTW && pv1.y != SENTW && pv1.z != SENTW && pv1.w != SENTW &&
                  pv2.x != SENTW && pv2.y != SENTW && pv2.z != SENTW && pv2.w != SENTW &&
                  pv3.x != SENTW && pv3.y != SENTW && pv3.z != SENTW && pv3.w != SENTW;
        if (__all(ok)) break;
        if (++tries > (1 << 16)) break;   // anti-hang bail
        __builtin_amdgcn_s_sleep(1);
        pv0 = ld_b128_dev(rowp + 0 + lg);
        pv1 = ld_b128_dev(rowp + 4 + lg);
        pv2 = ld_b128_dev(rowp + 8 + lg);
        pv3 = ld_b128_dev(rowp + 12 + lg);
      }
      __builtin_amdgcn_sched_barrier(0);   // rule #18: no MFMA hoist above wait

      half8 pa0 = __builtin_bit_cast(half8, pv0);
      half8 pa1 = __builtin_bit_cast(half8, pv1);
      half8 pa2 = __builtin_bit_cast(half8, pv2);
      half8 pa3 = __builtin_bit_cast(half8, pv3);
#pragma unroll
      for (int q = 0; q < 4; q++) acc[q] = __builtin_amdgcn_mfma_f32_16x16x32_f16(pa0, B[q][4], acc[q], 0, 0, 0);
#pragma unroll
      for (int q = 0; q < 4; q++) acc[q] = __builtin_amdgcn_mfma_f32_16x16x32_f16(pa1, B[q][5], acc[q], 0, 0, 0);
#pragma unroll
      for (int q = 0; q < 4; q++) acc[q] = __builtin_amdgcn_mfma_f32_16x16x32_f16(pa2, B[q][6], acc[q], 0, 0, 0);
#pragma unroll
      for (int q = 0; q < 4; q++) acc[q] = __builtin_amdgcn_mfma_f32_16x16x32_f16(pa3, B[q][7], acc[q], 0, 0, 0);
    }

    if (t + 1 < 1024) {   // zx prefetch AFTER the poll (kept out of poll vmcnt)
      const int tn = d ? tt - 1 : tt + 1;
#pragma unroll
      for (int q = 0; q < 4; q++)
        zq[q] = *(const ushort4v*)(zx + (((size_t)tn << 10 | (q * 256 + ug)) << 6) + b0 + lg * 4);
    }

    // gates + state update; D-frag: row(b_local) = lg*4+rr, col(u) = l16
    unsigned short hb16[4];
    float hf[4];
#pragma unroll
    for (int rr = 0; rr < 4; rr++) {
      const float zi = acc[0][rr], zf = acc[1][rr], zg = acc[2][rr], zo = acc[3][rr];
      const float cc = sigf(zf) * c[rr] + sigf(zi) * tanhf_(zg);
      c[rr] = cc;
      hf[rr] = sigf(zo) * tanhf_(cc);
      hb16[rr] = f2h(hf[rr]);
    }

    // publish partner-visible h (pack lane-pairs into 4B device stores)
    {
      unsigned prt[4];
#pragma unroll
      for (int rr = 0; rr < 4; rr++)
        prt[rr] = (unsigned)__shfl_xor((int)(unsigned)hb16[rr], 1);
      const int odd = l16 & 1;
      const int rb = odd ? 2 : 0;
#pragma unroll
      for (int k = 0; k < 2; k++) {
        const int rr = rb + k;
        const int bl = lg * 4 + rr;
        const unsigned lo = odd ? prt[rr] : (unsigned)hb16[rr];
        const unsigned hi = odd ? (unsigned)hb16[rr] : prt[rr];
        const unsigned pk = (lo & 0xffffu) | (hi << 16);
        if constexpr (LAYER == 1) {
          const size_t widx = (((size_t)tt * 64 + b0 + bl) * 512 + d * 256 + (ug & ~1)) >> 1;
          st_b32_dev((unsigned*)exch + widx, pk);
        } else {
          const size_t base = ((((size_t)t * 2 + d) * 4 + g) * 2 + half) * 2048;
          const size_t widx = (base + (size_t)bl * 128 + ((ug & ~1) - half * 128)) >> 1;
          st_b32_dev((unsigned*)exch + widx, pk);
        }
      }
    }

    if constexpr (LAYER == 2) {
#pragma unroll
      for (int rr = 0; rr < 4; rr++) {
        const int b = b0 + lg * 4 + rr;
        out[((size_t)b << 10 | tt) * 512 + d * 256 + ug] = hf[rr];
      }
    }

    // own-half h(t) -> LDS (slot t&1; read next step from this slot)
#pragma unroll
    for (int rr = 0; rr < 4; rr++) {
      const int bl = lg * 4 + rr;
      const int ul = wv * 16 + l16;
      const int idx = ((bl * 128 + ul) ^ ((bl & 7) << 3)) + (t & 1) * 2048;
      hlds[idx] = hb16[rr];
    }

    // raw barrier: only LDS ordering (no vmcnt drain -> polls/stores fly on)
    asm volatile("s_waitcnt lgkmcnt(0)" ::: "memory");
    __builtin_amdgcn_s_barrier();
  }
}

// LayerNorm over 512 features; one wave per row. f16 in/out, f32 math.
__global__ __launch_bounds__(256) void k_ln(
    const unsigned short* __restrict__ h1, const float* __restrict__ gamma,
    const float* __restrict__ beta, unsigned short* __restrict__ ln1) {
  const int tid = threadIdx.x, w = tid >> 6, l = tid & 63;
  const size_t row = (size_t)blockIdx.x * 4 + w;
  const unsigned short* src = h1 + row * 512 + l * 8;
  const ushort4v v0 = *(const ushort4v*)src;
  const ushort4v v1 = *(const ushort4v*)(src + 4);
  float xv[8] = {h2f(v0.x), h2f(v0.y), h2f(v0.z), h2f(v0.w),
                 h2f(v1.x), h2f(v1.y), h2f(v1.z), h2f(v1.w)};
  float sum = 0.f, ssq = 0.f;
#pragma unroll
  for (int i = 0; i < 8; i++) { sum += xv[i]; ssq += xv[i] * xv[i]; }
#pragma unroll
  for (int off = 32; off; off >>= 1) {
    sum += __shfl_xor(sum, off);
    ssq += __shfl_xor(ssq, off);
  }
  const float mu = sum * (1.f / 512.f);
  const float var = ssq * (1.f / 512.f) - mu * mu;
  const float rs = __builtin_amdgcn_rsqf(var + 1e-3f);
  const f32x4 g0 = *(const f32x4*)(gamma + l * 8);
  const f32x4 g1 = *(const f32x4*)(gamma + l * 8 + 4);
  const f32x4 e0 = *(const f32x4*)(beta + l * 8);
  const f32x4 e1 = *(const f32x4*)(beta + l * 8 + 4);
  float gg[8] = {g0.x, g0.y, g0.z, g0.w, g1.x, g1.y, g1.z, g1.w};
  float ee[8] = {e0.x, e0.y, e0.z, e0.w, e1.x, e1.y, e1.z, e1.w};
  unsigned short hh[8];
#pragma unroll
  for (int i = 0; i < 8; i++)
    hh[i] = f2h((xv[i] - mu) * rs * gg[i] + ee[i]);
  unsigned short* dst = ln1 + row * 512 + l * 8;
  *(ushort4v*)dst = (ushort4v){hh[0], hh[1], hh[2], hh[3]};
  *(ushort4v*)(dst + 4) = (ushort4v){hh[4], hh[5], hh[6], hh[7]};
}

extern "C" void kernel_launch(void* const* d_in, const int* in_sizes, int n_in,
                              void* d_out, int out_size, void* d_ws, size_t ws_size,
                              hipStream_t stream) {
  (void)in_sizes; (void)n_in; (void)out_size; (void)ws_size;
  const float* x     = (const float*)d_in[0];
  const float* W1f   = (const float*)d_in[1];
  const float* U1f   = (const float*)d_in[2];
  const float* b1f   = (const float*)d_in[3];
  const float* W1b   = (const float*)d_in[4];
  const float* U1b   = (const float*)d_in[5];
  const float* b1b   = (const float*)d_in[6];
  const float* gamma = (const float*)d_in[7];
  const float* beta  = (const float*)d_in[8];
  const float* W2f   = (const float*)d_in[9];
  const float* U2f   = (const float*)d_in[10];
  const float* b2f   = (const float*)d_in[11];
  const float* W2b   = (const float*)d_in[12];
  const float* U2b   = (const float*)d_in[13];
  const float* b2b   = (const float*)d_in[14];

  char* ws = (char*)d_ws;
  size_t ofs = 0;
  auto alloc = [&](size_t bytes) -> void* {
    void* p = ws + ofs;
    ofs += (bytes + 255) & ~(size_t)255;
    return p;
  };
  unsigned short* Wt1f  = (unsigned short*)alloc((size_t)1024*128*2);
  unsigned short* Wt1b  = (unsigned short*)alloc((size_t)1024*128*2);
  unsigned short* Ut1f  = (unsigned short*)alloc((size_t)1024*256*2);
  unsigned short* Ut1b  = (unsigned short*)alloc((size_t)1024*256*2);
  unsigned short* Ut2f  = (unsigned short*)alloc((size_t)1024*256*2);
  unsigned short* Ut2b  = (unsigned short*)alloc((size_t)1024*256*2);
  unsigned short* Wt2f  = (unsigned short*)alloc((size_t)1024*512*2);
  unsigned short* Wt2b  = (unsigned short*)alloc((size_t)1024*512*2);
  unsigned short* zxf   = (unsigned short*)alloc((size_t)1024*1024*64*2);  // 128MB
  unsigned short* zxb   = (unsigned short*)alloc((size_t)1024*1024*64*2);  // 128MB
  const size_t HH2_BYTES = (size_t)1024 * 2 * 4 * 2 * 16 * 128 * 2;        // 64MB
  unsigned short* hist  = (unsigned short*)alloc(HH2_BYTES);               // (ws >= 325MB, proven R5)

  // d_out (128MB) doubles as scratch with time-disjoint lifetimes:
  //   xb (16MB, dead after zx1) -> h1 (64MB, sentinel-filled, exchange+output
  //   of k_rec2<1>, dead after LN) ; ln1 at +64MB (dead after zx2); final f32
  //   output overwrites everything in k_rec2<2>.
  unsigned short* xb  = (unsigned short*)d_out;
  unsigned short* h1  = (unsigned short*)d_out;
  unsigned short* ln1 = (unsigned short*)d_out + (size_t)65536 * 512;

  k_transpose<<<1024 * 128 / 256, 256, 0, stream>>>(W1f, Wt1f, 128);
  k_transpose<<<1024 * 128 / 256, 256, 0, stream>>>(W1b, Wt1b, 128);
  k_transpose<<<1024 * 256 / 256, 256, 0, stream>>>(U1f, Ut1f, 256);
  k_transpose<<<1024 * 256 / 256, 256, 0, stream>>>(U1b, Ut1b, 256);
  k_transpose<<<1024 * 512 / 256, 256, 0, stream>>>(W2f, Wt2f, 512);
  k_transpose<<<1024 * 512 / 256, 256, 0, stream>>>(W2b, Wt2b, 512);
  k_transpose<<<1024 * 256 / 256, 256, 0, stream>>>(U2f, Ut2f, 256);
  k_transpose<<<1024 * 256 / 256, 256, 0, stream>>>(U2b, Ut2b, 256);
  k_cvtx<<<8192, 256, 0, stream>>>(x, xb);

  dim3 zgrid(512, 8, 2);
  k_zx<128><<<zgrid, 256, 0, stream>>>(xb, Wt1f, Wt1b, b1f, b1b, zxf, zxb);
  k_fill<<<2048, 256, 0, stream>>>((uint4v*)h1, 65536u * 512u / 8u);
  k_rec2<1><<<16, 512, 0, stream>>>(zxf, zxb, Ut1f, Ut1b, h1, nullptr);
  k_ln<<<65536 / 4, 256, 0, stream>>>(h1, gamma, beta, ln1);
  k_zx<512><<<zgrid, 256, 0, stream>>>(ln1, Wt2f, Wt2b, b2f, b2b, zxf, zxb);
  k_fill<<<2048, 256, 0, stream>>>((uint4v*)hist, (unsigned)(HH2_BYTES / 16));
  k_rec2<2><<<16, 512, 0, stream>>>(zxf, zxb, Ut2f, Ut2b, hist, (float*)d_out);
}